// Round 10
// baseline (1768.963 us; speedup 1.0000x reference)
//
#include <hip/hip_runtime.h>

typedef __attribute__((ext_vector_type(8))) short short8;
typedef __attribute__((ext_vector_type(4))) float f32x4;

#define NEGV -10000.0f

__device__ __forceinline__ float bfu2f(unsigned short u) {
  unsigned int x = ((unsigned int)u) << 16;
  return __builtin_bit_cast(float, x);
}
__device__ __forceinline__ unsigned short f2bfu(float f) {
  unsigned int x = __builtin_bit_cast(unsigned int, f);
  x += 0x7fffu + ((x >> 16) & 1u);
  return (unsigned short)(x >> 16);
}
__device__ __forceinline__ float fsig(float x) {
  return 1.0f / (1.0f + __expf(-x));
}
__device__ __forceinline__ float ftanh(float x) {
  x = fminf(15.0f, fmaxf(-15.0f, x));
  float e = __expf(-2.0f * x);
  return (1.0f - e) / (1.0f + e);
}

// ---------------- prep: convert weights to bf16, build combined bias ----------------
__global__ __launch_bounds__(256) void prep_kernel(
    const float* __restrict__ wihf, const float* __restrict__ wihb,
    const float* __restrict__ whhf, const float* __restrict__ whhb,
    const float* __restrict__ wo, const float* __restrict__ bfv,
    const float* __restrict__ bbv,
    unsigned short* __restrict__ wih_c, unsigned short* __restrict__ whh_c,
    unsigned short* __restrict__ wout_c, float* __restrict__ bias_c) {
  size_t i = (size_t)blockIdx.x * 256 + threadIdx.x;
  const size_t n_half = 2048u * 512u;
  const size_t n_wih = 2u * n_half;
  const size_t n_wo = 24u * 1024u;
  if (i < n_wih) {
    float v = (i < n_half) ? wihf[i] : wihb[i - n_half];
    wih_c[i] = f2bfu(v);
  } else if (i < 2u * n_wih) {
    size_t j = i - n_wih;
    float v = (j < n_half) ? whhf[j] : whhb[j - n_half];
    whh_c[j] = f2bfu(v);
  } else if (i < 2u * n_wih + n_wo) {
    size_t j = i - 2u * n_wih;
    wout_c[j] = f2bfu(wo[j]);
  } else if (i < 2u * n_wih + n_wo + 4096u) {
    size_t j = i - 2u * n_wih - n_wo;
    bias_c[j] = (j < 2048u) ? bfv[j] : bbv[j - 2048u];
  }
}

// ---------------- fused GEMM (producer) + persistent LSTM scan (consumer) ----------------
// Grid = 4608 wgs x 256 thr.
//   gid < 4096: GEMM tile. bx=gid>>5 (m, both-ends-first remap), by=gid&31 (n).
//     xg[16384][4096] = bf16(emb[xw[m]]) @ wih^T + bias, C-stores sc0 sc1
//     (IF$ write-through, visible device-wide -> xg sentinel protocol works).
//   gid >= 4096: scan wave (threads 64..255 exit). wid=gid-4096: dir=wid&1,
//     g=(wid>>1)&63, wv=(wid>>7)&3. R5-proven step: poll-on-data h protocol,
//     all h traffic sc0 sc1, issue->vmcnt(0)->sched_barrier->check (R7 rule).
//     xg also sentinel-polled (poisoned 0xFFFF; preactivations never NaN):
//     loads issued top-of-step, drained by the h-poll's vmcnt(0), checked after.
// Deadlock-free: scan wgs hold ~2 waves/CU; GEMM wgs (dependency-free) always
// have room to launch; all 512 scan wgs become co-resident as GEMM drains.
// Correct under ANY dispatch order (sentinels gate all cross-wg data).
__global__ __launch_bounds__(256, 1) void fused_kernel(
    const int* __restrict__ xw,             // [16384]
    const float* __restrict__ emb,          // [50000][512] f32
    const unsigned short* __restrict__ wih, // [4096][512] bf16
    const float* __restrict__ bias,         // [4096]
    const unsigned short* __restrict__ whh, // [2][2048][512] bf16
    unsigned short* __restrict__ xg,        // [16384][4096] bf16 (poisoned)
    unsigned short* __restrict__ hfp,
    unsigned short* __restrict__ hbp) {
  __shared__ alignas(16) char As[16384];
  __shared__ alignas(16) char Bs[16384];
  int gid = blockIdx.x;
  if (gid < 4096) {
    // ================= GEMM producer =================
    int bx = gid >> 5, by = gid & 31;
    int m_eff = (bx & 1) ? (127 - (bx >> 1)) : (bx >> 1);  // both ends first
    int m0 = m_eff * 128, n0 = by * 128;
    int tid = threadIdx.x;
    int wv = tid >> 6, l = tid & 63;
    int wm = wv >> 1, wn = wv & 1;
    int col = l & 15, quad = l >> 4;
    int tok[4];
#pragma unroll
    for (int q = 0; q < 4; ++q) tok[q] = xw[m0 + ((q * 4096 + tid * 16) >> 7)];
    f32x4 zero4 = {0.f, 0.f, 0.f, 0.f};
    f32x4 acc[4][4];
#pragma unroll
    for (int i = 0; i < 4; ++i)
#pragma unroll
      for (int j = 0; j < 4; ++j) acc[i][j] = zero4;
    for (int kt = 0; kt < 8; ++kt) {
#pragma unroll
      for (int q = 0; q < 4; ++q) {
        int o = q * 4096 + tid * 16;
        int row = o >> 7;
        int cb = o & 127;
        int swz = cb ^ ((row & 7) << 4);
        const float* sa = emb + (size_t)tok[q] * 512 + kt * 64 + (cb >> 1);
        f32x4 f0 = *(const f32x4*)sa;
        f32x4 f1 = *(const f32x4*)(sa + 4);
        short8 va;
#pragma unroll
        for (int j = 0; j < 4; ++j) {
          va[j] = (short)f2bfu(f0[j]);
          va[4 + j] = (short)f2bfu(f1[j]);
        }
        *(short8*)(As + row * 128 + swz) = va;
        short8 vb = *(const short8*)(wih + (size_t)(n0 + row) * 512 + kt * 64 + (cb >> 1));
        *(short8*)(Bs + row * 128 + swz) = vb;
      }
      __syncthreads();
#pragma unroll
      for (int kk = 0; kk < 2; ++kk) {
        short8 af[4], bf8[4];
#pragma unroll
        for (int mi = 0; mi < 4; ++mi) {
          int r = wm * 64 + mi * 16 + col;
          int cb = kk * 64 + quad * 16;
          af[mi] = *(const short8*)(As + r * 128 + (cb ^ ((r & 7) << 4)));
        }
#pragma unroll
        for (int ni = 0; ni < 4; ++ni) {
          int r = wn * 64 + ni * 16 + col;
          int cb = kk * 64 + quad * 16;
          bf8[ni] = *(const short8*)(Bs + r * 128 + (cb ^ ((r & 7) << 4)));
        }
#pragma unroll
        for (int mi = 0; mi < 4; ++mi)
#pragma unroll
          for (int ni = 0; ni < 4; ++ni)
            acc[mi][ni] = __builtin_amdgcn_mfma_f32_16x16x32_bf16(af[mi], bf8[ni], acc[mi][ni], 0, 0, 0);
      }
      __syncthreads();
    }
#pragma unroll
    for (int ni = 0; ni < 4; ++ni) {
      int cg = n0 + wn * 64 + ni * 16 + col;
      float bv = bias[cg];
#pragma unroll
      for (int mi = 0; mi < 4; ++mi) {
#pragma unroll
        for (int r = 0; r < 4; ++r) {
          int rg = m0 + wm * 64 + mi * 16 + quad * 4 + r;
          unsigned int cv = f2bfu(acc[mi][ni][r] + bv);
          unsigned short* cp = xg + (size_t)rg * 4096 + cg;
          asm volatile("global_store_short %0, %1, off sc0 sc1" ::"v"(cp), "v"(cv) : "memory");
        }
      }
    }
  } else {
    // ================= scan consumer =================
    if (threadIdx.x >= 64) return;
    int wid = gid - 4096;
    int l = threadIdx.x;
    int dir = wid & 1;
    int g = (wid >> 1) & 63;
    int wv = (wid >> 7) & 3;
    int u0 = g * 8;
    int col = l & 15, quad = l >> 4;
    int b_row = wv * 16 + quad * 4;
    unsigned short* tbuf = (unsigned short*)As;  // 256B transpose scratch
    // asm-resident w_hh fragments: 2 gate-pairs x 16 K-chunks
    short8 bfr[2][16];
#pragma unroll
    for (int n = 0; n < 2; ++n) {
      int blk = n * 2 + (col >> 3);  // 0..3 = i,f,g,o
      int gr = blk * 512 + u0 + (col & 7);
      const char* base = (const char*)(whh + ((size_t)dir * 2048 + gr) * 512 + quad * 8);
#pragma unroll
      for (int kk = 0; kk < 16; ++kk)
        asm volatile("global_load_dwordx4 %0, %1, off" : "=v"(bfr[n][kk]) : "v"(base + kk * 64));
    }
    asm volatile("s_waitcnt vmcnt(0)" ::: "memory");
    unsigned short* hseq = dir ? hbp : hfp;
    int gc0 = dir * 2048 + (col >> 3) * 512 + u0 + (col & 7);  // i/f col; +1024 elems = g/o
    float cst[4] = {0.f, 0.f, 0.f, 0.f};
    f32x4 zero4 = {0.f, 0.f, 0.f, 0.f};
    short8 af[16];
    unsigned int xv[8];
    for (int s = 0; s < 256; ++s) {
      int t_ = dir ? (255 - s) : s;
      // issue this step's xg loads (latency hidden under the h poll)
#pragma unroll
      for (int r = 0; r < 4; ++r) {
        const char* xa = (const char*)(xg + ((size_t)t_ * 64 + b_row + r) * 4096 + gc0);
        asm volatile("global_load_ushort %0, %1, off sc0 sc1" : "=v"(xv[r]) : "v"(xa));
        asm volatile("global_load_ushort %0, %1, off sc0 sc1" : "=v"(xv[4 + r]) : "v"(xa + 2048));
      }
      f32x4 a0 = zero4, a1 = zero4;
      if (s > 0) {
        int tprev = t_ + (dir ? 1 : -1);
        const char* pbase = (const char*)hseq + (size_t)tprev * 65536 + quad * 1024 +
                            (wv * 16 + col) * 16;
        unsigned long long bal;
        do {
#pragma unroll
          for (int kk = 0; kk < 16; ++kk)
            asm volatile("global_load_dwordx4 %0, %1, off sc0 sc1" : "=v"(af[kk]) : "v"(pbase + kk * 4096));
          asm volatile("s_waitcnt vmcnt(0)" ::: "memory");
          __builtin_amdgcn_sched_barrier(0);
          unsigned int st = 0u;
#pragma unroll
          for (int kk = 0; kk < 16; ++kk)
            st |= (((unsigned short)af[kk][0]) == 0xFFFFu) ? 1u : 0u;
          bal = __ballot(st != 0u);
        } while (bal != 0ull);
      } else {
        asm volatile("s_waitcnt vmcnt(0)" ::: "memory");
        __builtin_amdgcn_sched_barrier(0);
      }
      // xg sentinel check (regs already drained by the vmcnt(0) above)
      {
        unsigned int stx = 0u;
#pragma unroll
        for (int r = 0; r < 8; ++r) stx |= (xv[r] == 0xFFFFu) ? 1u : 0u;
        unsigned long long balx = __ballot(stx != 0u);
        while (balx != 0ull) {
#pragma unroll
          for (int r = 0; r < 4; ++r) {
            const char* xa = (const char*)(xg + ((size_t)t_ * 64 + b_row + r) * 4096 + gc0);
            asm volatile("global_load_ushort %0, %1, off sc0 sc1" : "=v"(xv[r]) : "v"(xa));
            asm volatile("global_load_ushort %0, %1, off sc0 sc1" : "=v"(xv[4 + r]) : "v"(xa + 2048));
          }
          asm volatile("s_waitcnt vmcnt(0)" ::: "memory");
          __builtin_amdgcn_sched_barrier(0);
          stx = 0u;
#pragma unroll
          for (int r = 0; r < 8; ++r) stx |= (xv[r] == 0xFFFFu) ? 1u : 0u;
          balx = __ballot(stx != 0u);
        }
      }
      if (s > 0) {
#pragma unroll
        for (int kk = 0; kk < 16; ++kk) {
          a0 = __builtin_amdgcn_mfma_f32_16x16x32_bf16(af[kk], bfr[0][kk], a0, 0, 0, 0);
          a1 = __builtin_amdgcn_mfma_f32_16x16x32_bf16(af[kk], bfr[1][kk], a1, 0, 0, 0);
        }
      }
      // gates; low/high lane pairs compute identical h, low lanes write LDS
      {
        bool low = (col < 8);
#pragma unroll
        for (int r = 0; r < 4; ++r) {
          float g0 = a0[r] + bfu2f((unsigned short)xv[r]);
          float g1 = a1[r] + bfu2f((unsigned short)xv[4 + r]);
          float p0 = __shfl_xor(g0, 8);
          float p1 = __shfl_xor(g1, 8);
          float iv = low ? g0 : p0;
          float fv = low ? p0 : g0;
          float gv = low ? g1 : p1;
          float ov = low ? p1 : g1;
          float cn = fsig(fv) * cst[r] + fsig(iv) * ftanh(gv);
          cst[r] = cn;
          float hv = fsig(ov) * ftanh(cn);
          if (low) tbuf[(quad * 4 + r) * 8 + (col & 7)] = f2bfu(hv);
        }
      }
      // wave-internal transpose readback (same wave: lgkmcnt suffices)
      asm volatile("s_waitcnt lgkmcnt(0)" ::: "memory");
      if (l < 16) {
        short8 hrow = *(const short8*)(tbuf + l * 8);
        char* dst = (char*)hseq + (size_t)t_ * 65536 + g * 1024 + (wv * 16 + l) * 16;
        asm volatile("global_store_dwordx4 %0, %1, off sc0 sc1" ::"v"(dst), "v"(hrow) : "memory");
      }
    }
  }
}

// ---------------- logits[t][b][k] = (hf|hb).w_out[k] + b_out, masked ----------------
__global__ __launch_bounds__(256) void logits_kernel(
    const unsigned short* __restrict__ hfp, const unsigned short* __restrict__ hbp,
    const unsigned short* __restrict__ wout, const float* __restrict__ bout,
    const int* __restrict__ y0, float* __restrict__ lg) {
  int t = blockIdx.x, tid = threadIdx.x;
  int b = tid >> 2, ks = tid & 3;
  int ytag = y0[(t + 1) * 64 + b];
  float mk = (ytag > 0) ? 1.f : 0.f;
  float av[6] = {0.f, 0.f, 0.f, 0.f, 0.f, 0.f};
  const char* pf = (const char*)hfp + (size_t)t * 65536;
  const char* pb = (const char*)hbp + (size_t)t * 65536;
  for (int uc = 0; uc < 64; ++uc) {
    short8 hv = *(const short8*)(pf + uc * 1024 + b * 16);
#pragma unroll
    for (int kk = 0; kk < 6; ++kk) {
      int k = ks * 6 + kk;
      short8 wv = *(const short8*)(wout + (size_t)k * 1024 + uc * 8);
#pragma unroll
      for (int j = 0; j < 8; ++j)
        av[kk] += bfu2f((unsigned short)hv[j]) * bfu2f((unsigned short)wv[j]);
    }
  }
  for (int uc = 0; uc < 64; ++uc) {
    short8 hv = *(const short8*)(pb + uc * 1024 + b * 16);
#pragma unroll
    for (int kk = 0; kk < 6; ++kk) {
      int k = ks * 6 + kk;
      short8 wv = *(const short8*)(wout + (size_t)k * 1024 + 512 + uc * 8);
#pragma unroll
      for (int j = 0; j < 8; ++j)
        av[kk] += bfu2f((unsigned short)hv[j]) * bfu2f((unsigned short)wv[j]);
    }
  }
#pragma unroll
  for (int kk = 0; kk < 6; ++kk) {
    int k = ks * 6 + kk;
    lg[((size_t)t * 64 + b) * 32 + k] = mk * (av[kk] + bout[k]);
  }
}

// ---------------- CRF forward + gold, one wave per batch ----------------
__global__ __launch_bounds__(64) void crf_kernel(
    const float* __restrict__ lg, const int* __restrict__ y0,
    const float* __restrict__ trans, float* __restrict__ res) {
  int b = blockIdx.x, l = threadIdx.x;
  __shared__ float tl[600];
  __shared__ float sc[24];
  for (int i = l; i < 576; i += 64) tl[(i / 24) * 25 + (i % 24)] = trans[i];
  if (l < 24) sc[l] = (l == 1) ? 0.f : NEGV;
  __syncthreads();
  float gold = 0.f;
  int lens = 0;
  for (int t = l; t < 256; t += 64) {
    int y1 = y0[(t + 1) * 64 + b];
    int yp = y0[t * 64 + b];
    if (y1 > 0) {
      gold += lg[((size_t)t * 64 + b) * 32 + y1] + tl[y1 * 25 + yp];
      lens += 1;
    }
  }
#pragma unroll
  for (int off = 32; off > 0; off >>= 1) {
    gold += __shfl_down(gold, off);
    lens += __shfl_down(lens, off);
  }
  gold = __shfl(gold, 0);
  lens = __shfl(lens, 0);
  int last = y0[lens * 64 + b];
  gold += tl[2 * 25 + last];
  int lc = (l < 24) ? l : 23;
  float trow[24];
#pragma unroll
  for (int j = 0; j < 24; ++j) trow[j] = tl[lc * 25 + j];
  for (int t = 0; t < 256; ++t) {
    int y1 = y0[(t + 1) * 64 + b];
    if (y1 > 0) {
      float ns = 0.f;
      if (l < 24) {
        float ht = lg[((size_t)t * 64 + b) * 32 + l];
        float mx = -3.0e38f;
        float sj[24];
#pragma unroll
        for (int j = 0; j < 24; ++j) {
          sj[j] = sc[j] + trow[j];
          mx = fmaxf(mx, sj[j]);
        }
        float sm = 0.f;
#pragma unroll
        for (int j = 0; j < 24; ++j) sm += __expf(sj[j] - mx);
        ns = ht + mx + __logf(sm);
      }
      __syncthreads();
      if (l < 24) sc[l] = ns;
      __syncthreads();
    }
  }
  float v = (l < 24) ? sc[l] + tl[2 * 25 + l] : -3.0e38f;
  float mx = v;
#pragma unroll
  for (int off = 32; off > 0; off >>= 1) mx = fmaxf(mx, __shfl_xor(mx, off));
  float se = (l < 24) ? __expf(v - mx) : 0.f;
#pragma unroll
  for (int off = 32; off > 0; off >>= 1) se += __shfl_xor(se, off);
  float Z = mx + __logf(se);
  if (l == 0) res[b] = Z - gold;
}

__global__ __launch_bounds__(64) void reduce_kernel(const float* __restrict__ res,
                                                    float* __restrict__ out) {
  int l = threadIdx.x;
  float v = res[l];
#pragma unroll
  for (int off = 32; off > 0; off >>= 1) v += __shfl_down(v, off);
  if (l == 0) out[0] = v * (1.0f / 64.0f);
}

extern "C" void kernel_launch(void* const* d_in, const int* in_sizes, int n_in,
                              void* d_out, int out_size, void* d_ws, size_t ws_size,
                              hipStream_t stream) {
  (void)in_sizes; (void)n_in; (void)out_size; (void)ws_size;
  const int* xw = (const int*)d_in[0];
  const int* y0 = (const int*)d_in[1];
  const float* emb = (const float*)d_in[2];
  const float* wihf = (const float*)d_in[3];
  const float* whhf = (const float*)d_in[4];
  const float* bfv = (const float*)d_in[5];
  const float* wihb = (const float*)d_in[6];
  const float* whhb = (const float*)d_in[7];
  const float* bbv = (const float*)d_in[8];
  const float* wo = (const float*)d_in[9];
  const float* bo = (const float*)d_in[10];
  const float* tr = (const float*)d_in[11];
  char* ws = (char*)d_ws;
  unsigned short* xg = (unsigned short*)(ws + 0);              // 134217728 B
  unsigned short* wih_c = (unsigned short*)(ws + 150994944);   // 4194304 B
  unsigned short* whh_c = (unsigned short*)(ws + 155189248);   // 4194304 B
  unsigned short* wout_c = (unsigned short*)(ws + 159383552);  // 49152 B
  float* bias_c = (float*)(ws + 159432704);                    // 16384 B
  unsigned short* hfp = (unsigned short*)(ws + 159449088);     // 16777216 B
  unsigned short* hbp = (unsigned short*)(ws + 176226304);     // 16777216 B
  float* lg = (float*)(ws + 193003520);                        // 2097152 B
  float* res = (float*)(ws + 195104768);                       // 256 B

  // pre-poison xg + h planes to 0xFFFF sentinels (data-is-flag protocol);
  // re-done every launch so graph replays are self-consistent.
  hipMemsetAsync(xg, 0xFF, 134217728, stream);
  hipMemsetAsync(hfp, 0xFF, 16777216, stream);
  hipMemsetAsync(hbp, 0xFF, 16777216, stream);
  prep_kernel<<<16496, 256, 0, stream>>>(wihf, wihb, whhf, whhb, wo, bfv, bbv,
                                         wih_c, whh_c, wout_c, bias_c);
  fused_kernel<<<4608, 256, 0, stream>>>(xw, emb, wih_c, bias_c, whh_c, xg, hfp, hbp);
  logits_kernel<<<256, 256, 0, stream>>>(hfp, hbp, wout_c, bo, y0, lg);
  crf_kernel<<<64, 64, 0, stream>>>(lg, y0, tr, res);
  reduce_kernel<<<1, 64, 0, stream>>>(res, (float*)d_out);
}

// Round 11
// 1183.314 us; speedup vs baseline: 1.4949x; 1.4949x over previous
//
#include <hip/hip_runtime.h>

typedef __attribute__((ext_vector_type(8))) short short8;
typedef __attribute__((ext_vector_type(4))) float f32x4;

#define NEGV -10000.0f

__device__ __forceinline__ float bfu2f(unsigned short u) {
  unsigned int x = ((unsigned int)u) << 16;
  return __builtin_bit_cast(float, x);
}
__device__ __forceinline__ unsigned short f2bfu(float f) {
  unsigned int x = __builtin_bit_cast(unsigned int, f);
  x += 0x7fffu + ((x >> 16) & 1u);
  return (unsigned short)(x >> 16);
}
__device__ __forceinline__ float fsig(float x) {
  return 1.0f / (1.0f + __expf(-x));
}
__device__ __forceinline__ float ftanh(float x) {
  x = fminf(15.0f, fmaxf(-15.0f, x));
  float e = __expf(-2.0f * x);
  return (1.0f - e) / (1.0f + e);
}

// ---------------- prep: convert weights to bf16, build combined bias ----------------
__global__ __launch_bounds__(256) void prep_kernel(
    const float* __restrict__ wihf, const float* __restrict__ wihb,
    const float* __restrict__ whhf, const float* __restrict__ whhb,
    const float* __restrict__ wo, const float* __restrict__ bfv,
    const float* __restrict__ bbv,
    unsigned short* __restrict__ wih_c, unsigned short* __restrict__ whh_c,
    unsigned short* __restrict__ wout_c, float* __restrict__ bias_c) {
  size_t i = (size_t)blockIdx.x * 256 + threadIdx.x;
  const size_t n_half = 2048u * 512u;
  const size_t n_wih = 2u * n_half;
  const size_t n_wo = 24u * 1024u;
  if (i < n_wih) {
    float v = (i < n_half) ? wihf[i] : wihb[i - n_half];
    wih_c[i] = f2bfu(v);
  } else if (i < 2u * n_wih) {
    size_t j = i - n_wih;
    float v = (j < n_half) ? whhf[j] : whhb[j - n_half];
    whh_c[j] = f2bfu(v);
  } else if (i < 2u * n_wih + n_wo) {
    size_t j = i - 2u * n_wih;
    wout_c[j] = f2bfu(wo[j]);
  } else if (i < 2u * n_wih + n_wo + 4096u) {
    size_t j = i - 2u * n_wih - n_wo;
    bias_c[j] = (j < 2048u) ? bfv[j] : bbv[j - 2048u];
  }
}

// ---------------- GEMM with fused gather:
// xg[16384][4096] = bf16(emb[xw[m]])[512] @ wih_c[4096][512]^T + bias ----
__global__ __launch_bounds__(256) void gemm_xg_kernel(
    const int* __restrict__ xw,             // [16384]
    const float* __restrict__ emb,          // [50000][512] f32
    const unsigned short* __restrict__ Bm,  // [4096][512] bf16
    const float* __restrict__ bias,         // [4096]
    unsigned short* __restrict__ C) {       // [16384][4096] bf16
  __shared__ alignas(16) char As[16384];
  __shared__ alignas(16) char Bs[16384];
  int m0 = blockIdx.x * 128, n0 = blockIdx.y * 128;
  int tid = threadIdx.x;
  int wv = tid >> 6, l = tid & 63;
  int wm = wv >> 1, wn = wv & 1;
  int col = l & 15, quad = l >> 4;
  int tok[4];
#pragma unroll
  for (int q = 0; q < 4; ++q) tok[q] = xw[m0 + ((q * 4096 + tid * 16) >> 7)];
  f32x4 zero4 = {0.f, 0.f, 0.f, 0.f};
  f32x4 acc[4][4];
#pragma unroll
  for (int i = 0; i < 4; ++i)
#pragma unroll
    for (int j = 0; j < 4; ++j) acc[i][j] = zero4;
  for (int kt = 0; kt < 8; ++kt) {
#pragma unroll
    for (int q = 0; q < 4; ++q) {
      int o = q * 4096 + tid * 16;
      int row = o >> 7;
      int cb = o & 127;
      int swz = cb ^ ((row & 7) << 4);
      const float* sa = emb + (size_t)tok[q] * 512 + kt * 64 + (cb >> 1);
      f32x4 f0 = *(const f32x4*)sa;
      f32x4 f1 = *(const f32x4*)(sa + 4);
      short8 va;
#pragma unroll
      for (int j = 0; j < 4; ++j) {
        va[j] = (short)f2bfu(f0[j]);
        va[4 + j] = (short)f2bfu(f1[j]);
      }
      *(short8*)(As + row * 128 + swz) = va;
      short8 vb = *(const short8*)(Bm + (size_t)(n0 + row) * 512 + kt * 64 + (cb >> 1));
      *(short8*)(Bs + row * 128 + swz) = vb;
    }
    __syncthreads();
#pragma unroll
    for (int kk = 0; kk < 2; ++kk) {
      short8 af[4], bf8[4];
#pragma unroll
      for (int mi = 0; mi < 4; ++mi) {
        int r = wm * 64 + mi * 16 + col;
        int cb = kk * 64 + quad * 16;
        af[mi] = *(const short8*)(As + r * 128 + (cb ^ ((r & 7) << 4)));
      }
#pragma unroll
      for (int ni = 0; ni < 4; ++ni) {
        int r = wn * 64 + ni * 16 + col;
        int cb = kk * 64 + quad * 16;
        bf8[ni] = *(const short8*)(Bs + r * 128 + (cb ^ ((r & 7) << 4)));
      }
#pragma unroll
      for (int mi = 0; mi < 4; ++mi)
#pragma unroll
        for (int ni = 0; ni < 4; ++ni)
          acc[mi][ni] = __builtin_amdgcn_mfma_f32_16x16x32_bf16(af[mi], bf8[ni], acc[mi][ni], 0, 0, 0);
    }
    __syncthreads();
  }
#pragma unroll
  for (int ni = 0; ni < 4; ++ni) {
    int cg = n0 + wn * 64 + ni * 16 + col;
    float bv = bias[cg];
#pragma unroll
    for (int mi = 0; mi < 4; ++mi) {
#pragma unroll
      for (int r = 0; r < 4; ++r) {
        int rg = m0 + wm * 64 + mi * 16 + quad * 4 + r;
        C[(size_t)rg * 4096 + cg] = f2bfu(acc[mi][ni][r] + bv);
      }
    }
  }
}

// ---------------- persistent LSTM scan: wave-decoupled, poll-on-data (R5-EXACT, proven) ----------------
// 512 wgs x 64 threads. Wave wid: dir=wid&1, g=(wid>>1)&63, wv=(wid>>7)&3.
// h planes pre-poisoned to 0xFFFF (bf16 NaN, unreachable: |h|<1). The data IS
// the flag: producers store 16B chunks (atomic at IF$) with sc0 sc1 and no
// drain; readers re-issue their 16 h-loads until no chunk starts with the
// sentinel. Poll safety: issue -> vmcnt(0) -> sched_barrier -> check; asm
// registers never consumed while loads in flight (R7 lesson).
__global__ __launch_bounds__(64, 1) void scan_kernel(
    const unsigned short* __restrict__ whh,  // [2][2048][512] bf16
    const unsigned short* __restrict__ xg,   // [16384][4096] bf16
    unsigned short* __restrict__ hfp,
    unsigned short* __restrict__ hbp) {
  __shared__ alignas(16) unsigned short tbuf[128];  // 256B transpose scratch
  int wid = blockIdx.x;
  int l = threadIdx.x;
  int dir = wid & 1;
  int g = (wid >> 1) & 63;
  int wv = (wid >> 7) & 3;
  int u0 = g * 8;
  int col = l & 15, quad = l >> 4;
  int b_row = wv * 16 + quad * 4;
  // asm-resident w_hh fragments: 2 gate-pairs x 16 K-chunks = 128 VGPRs
  short8 bfr[2][16];
#pragma unroll
  for (int n = 0; n < 2; ++n) {
    int blk = n * 2 + (col >> 3);  // 0..3 = i,f,g,o
    int gr = blk * 512 + u0 + (col & 7);
    const char* base = (const char*)(whh + ((size_t)dir * 2048 + gr) * 512 + quad * 8);
#pragma unroll
    for (int kk = 0; kk < 16; ++kk)
      asm volatile("global_load_dwordx4 %0, %1, off" : "=v"(bfr[n][kk]) : "v"(base + kk * 64));
  }
  asm volatile("s_waitcnt vmcnt(0)" ::: "memory");
  unsigned short* hseq = dir ? hbp : hfp;
  float cst[4] = {0.f, 0.f, 0.f, 0.f};
  f32x4 zero4 = {0.f, 0.f, 0.f, 0.f};
  for (int s = 0; s < 256; ++s) {
    int t = dir ? (255 - s) : s;
    // xg loads: plain cached, issued before the poll -> latency hidden
    float xgv[2][4];
#pragma unroll
    for (int n = 0; n < 2; ++n) {
      int gc = dir * 2048 + (n * 2 + (col >> 3)) * 512 + u0 + (col & 7);
#pragma unroll
      for (int r = 0; r < 4; ++r)
        xgv[n][r] = bfu2f(xg[((size_t)t * 64 + b_row + r) * 4096 + gc]);
    }
    f32x4 a0 = zero4, a1 = zero4;
    if (s > 0) {
      int tprev = dir ? (t + 1) : (t - 1);
      const char* pbase = (const char*)hseq + (size_t)tprev * 65536 + quad * 1024 +
                          (wv * 16 + col) * 16;
      short8 af[16];
      unsigned long long bal;
      do {
#pragma unroll
        for (int kk = 0; kk < 16; ++kk)
          asm volatile("global_load_dwordx4 %0, %1, off sc0 sc1" : "=v"(af[kk]) : "v"(pbase + kk * 4096));
        asm volatile("s_waitcnt vmcnt(0)" ::: "memory");
        unsigned int anystale = 0u;
#pragma unroll
        for (int kk = 0; kk < 16; ++kk)
          anystale |= (((unsigned short)af[kk][0]) == 0xFFFFu) ? 1u : 0u;
        bal = __ballot(anystale != 0u);
      } while (bal != 0ull);
      __builtin_amdgcn_sched_barrier(0);
#pragma unroll
      for (int kk = 0; kk < 16; ++kk) {
        a0 = __builtin_amdgcn_mfma_f32_16x16x32_bf16(af[kk], bfr[0][kk], a0, 0, 0, 0);
        a1 = __builtin_amdgcn_mfma_f32_16x16x32_bf16(af[kk], bfr[1][kk], a1, 0, 0, 0);
      }
    }
    // gates; low/high lane pairs compute identical h, low lanes write LDS
    {
      bool low = (col < 8);
#pragma unroll
      for (int r = 0; r < 4; ++r) {
        float g0 = a0[r] + xgv[0][r];
        float g1 = a1[r] + xgv[1][r];
        float p0 = __shfl_xor(g0, 8);
        float p1 = __shfl_xor(g1, 8);
        float iv = low ? g0 : p0;
        float fv = low ? p0 : g0;
        float gv = low ? g1 : p1;
        float ov = low ? p1 : g1;
        float cn = fsig(fv) * cst[r] + fsig(iv) * ftanh(gv);
        cst[r] = cn;
        float hv = fsig(ov) * ftanh(cn);
        if (low) tbuf[(quad * 4 + r) * 8 + (col & 7)] = f2bfu(hv);
      }
    }
    // wave-internal transpose readback (same wave: lgkmcnt suffices, no barrier)
    asm volatile("s_waitcnt lgkmcnt(0)" ::: "memory");
    if (l < 16) {
      short8 hrow = *(const short8*)(tbuf + l * 8);
      char* dst = (char*)hseq + (size_t)t * 65536 + g * 1024 + (wv * 16 + l) * 16;
      asm volatile("global_store_dwordx4 %0, %1, off sc0 sc1" :: "v"(dst), "v"(hrow) : "memory");
    }
    // no drain, no flag: the store IS the publish; it retires in background
  }
}

// ---------------- logits via MFMA: lg[t][b][k] = mask*( (hf|hb)@wout^T + bout ) ----------------
// One wg (4 waves) per t. Wave w: N-tile nt=w&1 (tags nt*16..+16), b-half
// mh=w>>1 (rows mh*32..+32 = 2 M-tiles). A-fragments are the h planes' native
// 16B chunks ([t][g'][b][8u], row=lane&15=b, k=(lane>>4)*8): zero rearrange.
// B-fragments: wout_c[tag][k] 16B reads, tag=lane&15 (clamped to 23; output
// cols 24..31 computed but never stored).
__global__ __launch_bounds__(256) void logits_kernel(
    const unsigned short* __restrict__ hfp, const unsigned short* __restrict__ hbp,
    const unsigned short* __restrict__ wout, const float* __restrict__ bout,
    const int* __restrict__ y0, float* __restrict__ lg) {
  int t = blockIdx.x;
  int w = threadIdx.x >> 6, l = threadIdx.x & 63;
  int nt = w & 1, mh = w >> 1;
  int col = l & 15, quad = l >> 4;
  // B fragments: 32 K-chunks (K=1024: kk<16 -> hf units, kk>=16 -> hb units)
  int wr = nt * 16 + col;
  if (wr > 23) wr = 23;
  short8 bw[32];
#pragma unroll
  for (int kk = 0; kk < 32; ++kk)
    bw[kk] = *(const short8*)(wout + (size_t)wr * 1024 + kk * 32 + quad * 8);
  f32x4 zero4 = {0.f, 0.f, 0.f, 0.f};
  const char* pf = (const char*)hfp + (size_t)t * 65536;
  const char* pb = (const char*)hbp + (size_t)t * 65536;
#pragma unroll
  for (int mt = 0; mt < 2; ++mt) {
    int b0 = mh * 32 + mt * 16;
    f32x4 acc = zero4;
#pragma unroll
    for (int kk = 0; kk < 16; ++kk) {
      short8 a = *(const short8*)(pf + (kk * 4 + quad) * 1024 + (b0 + col) * 16);
      acc = __builtin_amdgcn_mfma_f32_16x16x32_bf16(a, bw[kk], acc, 0, 0, 0);
    }
#pragma unroll
    for (int kk = 0; kk < 16; ++kk) {
      short8 a = *(const short8*)(pb + (kk * 4 + quad) * 1024 + (b0 + col) * 16);
      acc = __builtin_amdgcn_mfma_f32_16x16x32_bf16(a, bw[16 + kk], acc, 0, 0, 0);
    }
    // C layout: col=lane&15 -> tag, row=quad*4+r -> b offset
    int ko = nt * 16 + col;
    if (ko < 24) {
      float bv = bout[ko];
#pragma unroll
      for (int r = 0; r < 4; ++r) {
        int b = b0 + quad * 4 + r;
        float mk = (y0[(t + 1) * 64 + b] > 0) ? 1.f : 0.f;
        lg[((size_t)t * 64 + b) * 32 + ko] = mk * (acc[r] + bv);
      }
    }
  }
}

// ---------------- CRF forward + gold, one wave per batch ----------------
__global__ __launch_bounds__(64) void crf_kernel(
    const float* __restrict__ lg, const int* __restrict__ y0,
    const float* __restrict__ trans, float* __restrict__ res) {
  int b = blockIdx.x, l = threadIdx.x;
  __shared__ float tl[600];
  __shared__ float sc[24];
  for (int i = l; i < 576; i += 64) tl[(i / 24) * 25 + (i % 24)] = trans[i];
  if (l < 24) sc[l] = (l == 1) ? 0.f : NEGV;
  __syncthreads();
  float gold = 0.f;
  int lens = 0;
  for (int t = l; t < 256; t += 64) {
    int y1 = y0[(t + 1) * 64 + b];
    int yp = y0[t * 64 + b];
    if (y1 > 0) {
      gold += lg[((size_t)t * 64 + b) * 32 + y1] + tl[y1 * 25 + yp];
      lens += 1;
    }
  }
#pragma unroll
  for (int off = 32; off > 0; off >>= 1) {
    gold += __shfl_down(gold, off);
    lens += __shfl_down(lens, off);
  }
  gold = __shfl(gold, 0);
  lens = __shfl(lens, 0);
  int last = y0[lens * 64 + b];
  gold += tl[2 * 25 + last];
  int lc = (l < 24) ? l : 23;
  float trow[24];
#pragma unroll
  for (int j = 0; j < 24; ++j) trow[j] = tl[lc * 25 + j];
  for (int t = 0; t < 256; ++t) {
    int y1 = y0[(t + 1) * 64 + b];
    if (y1 > 0) {
      float ns = 0.f;
      if (l < 24) {
        float ht = lg[((size_t)t * 64 + b) * 32 + l];
        float mx = -3.0e38f;
        float sj[24];
#pragma unroll
        for (int j = 0; j < 24; ++j) {
          sj[j] = sc[j] + trow[j];
          mx = fmaxf(mx, sj[j]);
        }
        float sm = 0.f;
#pragma unroll
        for (int j = 0; j < 24; ++j) sm += __expf(sj[j] - mx);
        ns = ht + mx + __logf(sm);
      }
      __syncthreads();
      if (l < 24) sc[l] = ns;
      __syncthreads();
    }
  }
  float v = (l < 24) ? sc[l] + tl[2 * 25 + l] : -3.0e38f;
  float mx = v;
#pragma unroll
  for (int off = 32; off > 0; off >>= 1) mx = fmaxf(mx, __shfl_xor(mx, off));
  float se = (l < 24) ? __expf(v - mx) : 0.f;
#pragma unroll
  for (int off = 32; off > 0; off >>= 1) se += __shfl_xor(se, off);
  float Z = mx + __logf(se);
  if (l == 0) res[b] = Z - gold;
}

__global__ __launch_bounds__(64) void reduce_kernel(const float* __restrict__ res,
                                                    float* __restrict__ out) {
  int l = threadIdx.x;
  float v = res[l];
#pragma unroll
  for (int off = 32; off > 0; off >>= 1) v += __shfl_down(v, off);
  if (l == 0) out[0] = v * (1.0f / 64.0f);
}

extern "C" void kernel_launch(void* const* d_in, const int* in_sizes, int n_in,
                              void* d_out, int out_size, void* d_ws, size_t ws_size,
                              hipStream_t stream) {
  (void)in_sizes; (void)n_in; (void)out_size; (void)ws_size;
  const int* xw = (const int*)d_in[0];
  const int* y0 = (const int*)d_in[1];
  const float* emb = (const float*)d_in[2];
  const float* wihf = (const float*)d_in[3];
  const float* whhf = (const float*)d_in[4];
  const float* bfv = (const float*)d_in[5];
  const float* wihb = (const float*)d_in[6];
  const float* whhb = (const float*)d_in[7];
  const float* bbv = (const float*)d_in[8];
  const float* wo = (const float*)d_in[9];
  const float* bo = (const float*)d_in[10];
  const float* tr = (const float*)d_in[11];
  char* ws = (char*)d_ws;
  unsigned short* xg = (unsigned short*)(ws + 0);              // 134217728 B
  unsigned short* wih_c = (unsigned short*)(ws + 150994944);   // 4194304 B
  unsigned short* whh_c = (unsigned short*)(ws + 155189248);   // 4194304 B
  unsigned short* wout_c = (unsigned short*)(ws + 159383552);  // 49152 B
  float* bias_c = (float*)(ws + 159432704);                    // 16384 B
  unsigned short* hfp = (unsigned short*)(ws + 159449088);     // 16777216 B
  unsigned short* hbp = (unsigned short*)(ws + 176226304);     // 16777216 B
  float* lg = (float*)(ws + 193003520);                        // 2097152 B
  float* res = (float*)(ws + 195104768);                       // 256 B

  // pre-poison h planes to the 0xFFFF sentinel (data-is-flag protocol);
  // re-done every launch so graph replays are self-consistent.
  hipMemsetAsync(hfp, 0xFF, 16777216, stream);
  hipMemsetAsync(hbp, 0xFF, 16777216, stream);
  prep_kernel<<<16496, 256, 0, stream>>>(wihf, wihb, whhf, whhb, wo, bfv, bbv,
                                         wih_c, whh_c, wout_c, bias_c);
  gemm_xg_kernel<<<dim3(128, 32), 256, 0, stream>>>(xw, emb, wih_c, bias_c, xg);
  scan_kernel<<<512, 64, 0, stream>>>(whh_c, xg, hfp, hbp);
  logits_kernel<<<256, 256, 0, stream>>>(hfp, hbp, wout_c, bo, y0, lg);
  crf_kernel<<<64, 64, 0, stream>>>(lg, y0, tr, res);
  reduce_kernel<<<1, 64, 0, stream>>>(res, (float*)d_out);
}

// Round 12
// 1178.576 us; speedup vs baseline: 1.5009x; 1.0040x over previous
//
#include <hip/hip_runtime.h>

typedef __attribute__((ext_vector_type(8))) short short8;
typedef __attribute__((ext_vector_type(4))) float f32x4;

#define NEGV -10000.0f

__device__ __forceinline__ float bfu2f(unsigned short u) {
  unsigned int x = ((unsigned int)u) << 16;
  return __builtin_bit_cast(float, x);
}
__device__ __forceinline__ unsigned short f2bfu(float f) {
  unsigned int x = __builtin_bit_cast(unsigned int, f);
  x += 0x7fffu + ((x >> 16) & 1u);
  return (unsigned short)(x >> 16);
}
__device__ __forceinline__ float fsig(float x) {
  return 1.0f / (1.0f + __expf(-x));
}
__device__ __forceinline__ float ftanh(float x) {
  x = fminf(15.0f, fmaxf(-15.0f, x));
  float e = __expf(-2.0f * x);
  return (1.0f - e) / (1.0f + e);
}

// ---------------- prep: weights->bf16, combined bias, embedding gather ----------------
__global__ __launch_bounds__(256) void prep_kernel(
    const float* __restrict__ wihf, const float* __restrict__ wihb,
    const float* __restrict__ whhf, const float* __restrict__ whhb,
    const float* __restrict__ wo, const float* __restrict__ bfv,
    const float* __restrict__ bbv, const int* __restrict__ xw,
    const float* __restrict__ emb,
    unsigned short* __restrict__ wih_c, unsigned short* __restrict__ whh_c,
    unsigned short* __restrict__ wout_c, float* __restrict__ bias_c,
    unsigned short* __restrict__ xbf) {
  size_t i = (size_t)blockIdx.x * 256 + threadIdx.x;
  const size_t n_half = 2048u * 512u;        // 1048576
  const size_t n_wih = 2u * n_half;          // 2097152
  const size_t n_wo = 24u * 1024u;           // 24576
  const size_t TOT = 2u * n_wih + n_wo + 4096u;  // 4222976
  if (i < n_wih) {
    float v = (i < n_half) ? wihf[i] : wihb[i - n_half];
    wih_c[i] = f2bfu(v);
  } else if (i < 2u * n_wih) {
    size_t j = i - n_wih;
    float v = (j < n_half) ? whhf[j] : whhb[j - n_half];
    whh_c[j] = f2bfu(v);
  } else if (i < 2u * n_wih + n_wo) {
    size_t j = i - 2u * n_wih;
    wout_c[j] = f2bfu(wo[j]);
  } else if (i < TOT) {
    size_t j = i - 2u * n_wih - n_wo;
    bias_c[j] = (j < 2048u) ? bfv[j] : bbv[j - 2048u];
  } else if (i < TOT + 8388608u) {
    size_t j = i - TOT;
    int tb = (int)(j >> 9), e = (int)(j & 511u);
    xbf[j] = f2bfu(emb[(size_t)xw[tb] * 512 + e]);
  }
}

// ---------------- GEMM (m97 structure): xg = xbf @ wih_c^T + bias ----------------
// 128x128 tile, BK=64. Both operands staged via global_load_lds width-16:
// linear LDS dest + PRE-SWIZZLED global source (rule 21: the source permutation
// equals the read permutation). Read path identical to the proven R11 kernel:
// phys[r*128 + (cb ^ ((r&7)<<4))] == logical(r, cb).
__global__ __launch_bounds__(256) void gemm_xg_kernel(
    const unsigned short* __restrict__ A,   // xbf [16384][512] bf16
    const unsigned short* __restrict__ Bm,  // wih_c [4096][512] bf16
    const float* __restrict__ bias,         // [4096]
    unsigned short* __restrict__ C) {       // [16384][4096] bf16
  __shared__ alignas(16) char As[16384];
  __shared__ alignas(16) char Bs[16384];
  int m0 = blockIdx.x * 128, n0 = blockIdx.y * 128;
  int tid = threadIdx.x;
  int wv = tid >> 6, l = tid & 63;
  int wm = wv >> 1, wn = wv & 1;
  int col = l & 15, quad = l >> 4;
  // staging geometry (constant per thread): linear LDS offset o -> (row,p);
  // source fetches logical bytes (row, p ^ swz(row)).
  int src_off[4], lbase[4];
#pragma unroll
  for (int q = 0; q < 4; ++q) {
    int o = q * 4096 + tid * 16;
    int row = o >> 7, p = o & 127;
    src_off[q] = row * 1024 + (p ^ ((row & 7) << 4));  // bytes within panel
    lbase[q] = q * 4096 + wv * 1024;                   // wave-uniform LDS base
  }
  const char* abase = (const char*)A + (size_t)m0 * 1024;
  const char* bbase = (const char*)Bm + (size_t)n0 * 1024;
  f32x4 zero4 = {0.f, 0.f, 0.f, 0.f};
  f32x4 acc[4][4];
#pragma unroll
  for (int i = 0; i < 4; ++i)
#pragma unroll
    for (int j = 0; j < 4; ++j) acc[i][j] = zero4;
  for (int kt = 0; kt < 8; ++kt) {
#pragma unroll
    for (int q = 0; q < 4; ++q) {
      __builtin_amdgcn_global_load_lds(
          (const __attribute__((address_space(1))) void*)(abase + src_off[q] + kt * 128),
          (__attribute__((address_space(3))) void*)(As + lbase[q]), 16, 0, 0);
      __builtin_amdgcn_global_load_lds(
          (const __attribute__((address_space(1))) void*)(bbase + src_off[q] + kt * 128),
          (__attribute__((address_space(3))) void*)(Bs + lbase[q]), 16, 0, 0);
    }
    __syncthreads();  // compiler drains vmcnt before s_barrier (m97)
#pragma unroll
    for (int kk = 0; kk < 2; ++kk) {
      short8 af[4], bf8[4];
#pragma unroll
      for (int mi = 0; mi < 4; ++mi) {
        int r = wm * 64 + mi * 16 + col;
        int cb = kk * 64 + quad * 16;
        af[mi] = *(const short8*)(As + r * 128 + (cb ^ ((r & 7) << 4)));
      }
#pragma unroll
      for (int ni = 0; ni < 4; ++ni) {
        int r = wn * 64 + ni * 16 + col;
        int cb = kk * 64 + quad * 16;
        bf8[ni] = *(const short8*)(Bs + r * 128 + (cb ^ ((r & 7) << 4)));
      }
#pragma unroll
      for (int mi = 0; mi < 4; ++mi)
#pragma unroll
        for (int ni = 0; ni < 4; ++ni)
          acc[mi][ni] = __builtin_amdgcn_mfma_f32_16x16x32_bf16(af[mi], bf8[ni], acc[mi][ni], 0, 0, 0);
    }
    __syncthreads();
  }
#pragma unroll
  for (int ni = 0; ni < 4; ++ni) {
    int cg = n0 + wn * 64 + ni * 16 + col;
    float bv = bias[cg];
#pragma unroll
    for (int mi = 0; mi < 4; ++mi) {
#pragma unroll
      for (int r = 0; r < 4; ++r) {
        int rg = m0 + wm * 64 + mi * 16 + quad * 4 + r;
        C[(size_t)rg * 4096 + cg] = f2bfu(acc[mi][ni][r] + bv);
      }
    }
  }
}

// ---------------- persistent LSTM scan: wave-decoupled, poll-on-data (R5-EXACT, proven) ----------------
// 512 wgs x 64 threads. Wave wid: dir=wid&1, g=(wid>>1)&63, wv=(wid>>7)&3.
// h planes pre-poisoned to 0xFFFF (bf16 NaN, unreachable: |h|<1). The data IS
// the flag: producers store 16B chunks (atomic at IF$) with sc0 sc1 and no
// drain; readers re-issue their 16 h-loads until no chunk starts with the
// sentinel. Poll safety: issue -> vmcnt(0) -> check; asm registers never
// consumed while loads in flight (R7 lesson).
__global__ __launch_bounds__(64, 1) void scan_kernel(
    const unsigned short* __restrict__ whh,  // [2][2048][512] bf16
    const unsigned short* __restrict__ xg,   // [16384][4096] bf16
    unsigned short* __restrict__ hfp,
    unsigned short* __restrict__ hbp) {
  __shared__ alignas(16) unsigned short tbuf[128];  // 256B transpose scratch
  int wid = blockIdx.x;
  int l = threadIdx.x;
  int dir = wid & 1;
  int g = (wid >> 1) & 63;
  int wv = (wid >> 7) & 3;
  int u0 = g * 8;
  int col = l & 15, quad = l >> 4;
  int b_row = wv * 16 + quad * 4;
  // asm-resident w_hh fragments: 2 gate-pairs x 16 K-chunks = 128 VGPRs
  short8 bfr[2][16];
#pragma unroll
  for (int n = 0; n < 2; ++n) {
    int blk = n * 2 + (col >> 3);  // 0..3 = i,f,g,o
    int gr = blk * 512 + u0 + (col & 7);
    const char* base = (const char*)(whh + ((size_t)dir * 2048 + gr) * 512 + quad * 8);
#pragma unroll
    for (int kk = 0; kk < 16; ++kk)
      asm volatile("global_load_dwordx4 %0, %1, off" : "=v"(bfr[n][kk]) : "v"(base + kk * 64));
  }
  asm volatile("s_waitcnt vmcnt(0)" ::: "memory");
  unsigned short* hseq = dir ? hbp : hfp;
  float cst[4] = {0.f, 0.f, 0.f, 0.f};
  f32x4 zero4 = {0.f, 0.f, 0.f, 0.f};
  for (int s = 0; s < 256; ++s) {
    int t = dir ? (255 - s) : s;
    // xg loads: plain cached, issued before the poll -> latency hidden
    float xgv[2][4];
#pragma unroll
    for (int n = 0; n < 2; ++n) {
      int gc = dir * 2048 + (n * 2 + (col >> 3)) * 512 + u0 + (col & 7);
#pragma unroll
      for (int r = 0; r < 4; ++r)
        xgv[n][r] = bfu2f(xg[((size_t)t * 64 + b_row + r) * 4096 + gc]);
    }
    f32x4 a0 = zero4, a1 = zero4;
    if (s > 0) {
      int tprev = dir ? (t + 1) : (t - 1);
      const char* pbase = (const char*)hseq + (size_t)tprev * 65536 + quad * 1024 +
                          (wv * 16 + col) * 16;
      short8 af[16];
      unsigned long long bal;
      do {
#pragma unroll
        for (int kk = 0; kk < 16; ++kk)
          asm volatile("global_load_dwordx4 %0, %1, off sc0 sc1" : "=v"(af[kk]) : "v"(pbase + kk * 4096));
        asm volatile("s_waitcnt vmcnt(0)" ::: "memory");
        unsigned int anystale = 0u;
#pragma unroll
        for (int kk = 0; kk < 16; ++kk)
          anystale |= (((unsigned short)af[kk][0]) == 0xFFFFu) ? 1u : 0u;
        bal = __ballot(anystale != 0u);
      } while (bal != 0ull);
      __builtin_amdgcn_sched_barrier(0);
#pragma unroll
      for (int kk = 0; kk < 16; ++kk) {
        a0 = __builtin_amdgcn_mfma_f32_16x16x32_bf16(af[kk], bfr[0][kk], a0, 0, 0, 0);
        a1 = __builtin_amdgcn_mfma_f32_16x16x32_bf16(af[kk], bfr[1][kk], a1, 0, 0, 0);
      }
    }
    // gates; low/high lane pairs compute identical h, low lanes write LDS
    {
      bool low = (col < 8);
#pragma unroll
      for (int r = 0; r < 4; ++r) {
        float g0 = a0[r] + xgv[0][r];
        float g1 = a1[r] + xgv[1][r];
        float p0 = __shfl_xor(g0, 8);
        float p1 = __shfl_xor(g1, 8);
        float iv = low ? g0 : p0;
        float fv = low ? p0 : g0;
        float gv = low ? g1 : p1;
        float ov = low ? p1 : g1;
        float cn = fsig(fv) * cst[r] + fsig(iv) * ftanh(gv);
        cst[r] = cn;
        float hv = fsig(ov) * ftanh(cn);
        if (low) tbuf[(quad * 4 + r) * 8 + (col & 7)] = f2bfu(hv);
      }
    }
    // wave-internal transpose readback (same wave: lgkmcnt suffices, no barrier)
    asm volatile("s_waitcnt lgkmcnt(0)" ::: "memory");
    if (l < 16) {
      short8 hrow = *(const short8*)(tbuf + l * 8);
      char* dst = (char*)hseq + (size_t)t * 65536 + g * 1024 + (wv * 16 + l) * 16;
      asm volatile("global_store_dwordx4 %0, %1, off sc0 sc1" :: "v"(dst), "v"(hrow) : "memory");
    }
    // no drain, no flag: the store IS the publish; it retires in background
  }
}

// ---------------- logits via MFMA: lg[t][b][k] = mask*( (hf|hb)@wout^T + bout ) ----------------
__global__ __launch_bounds__(256) void logits_kernel(
    const unsigned short* __restrict__ hfp, const unsigned short* __restrict__ hbp,
    const unsigned short* __restrict__ wout, const float* __restrict__ bout,
    const int* __restrict__ y0, float* __restrict__ lg) {
  int t = blockIdx.x;
  int w = threadIdx.x >> 6, l = threadIdx.x & 63;
  int nt = w & 1, mh = w >> 1;
  int col = l & 15, quad = l >> 4;
  int wr = nt * 16 + col;
  if (wr > 23) wr = 23;
  short8 bw[32];
#pragma unroll
  for (int kk = 0; kk < 32; ++kk)
    bw[kk] = *(const short8*)(wout + (size_t)wr * 1024 + kk * 32 + quad * 8);
  f32x4 zero4 = {0.f, 0.f, 0.f, 0.f};
  const char* pf = (const char*)hfp + (size_t)t * 65536;
  const char* pb = (const char*)hbp + (size_t)t * 65536;
#pragma unroll
  for (int mt = 0; mt < 2; ++mt) {
    int b0 = mh * 32 + mt * 16;
    f32x4 acc = zero4;
#pragma unroll
    for (int kk = 0; kk < 16; ++kk) {
      short8 a = *(const short8*)(pf + (kk * 4 + quad) * 1024 + (b0 + col) * 16);
      acc = __builtin_amdgcn_mfma_f32_16x16x32_bf16(a, bw[kk], acc, 0, 0, 0);
    }
#pragma unroll
    for (int kk = 0; kk < 16; ++kk) {
      short8 a = *(const short8*)(pb + (kk * 4 + quad) * 1024 + (b0 + col) * 16);
      acc = __builtin_amdgcn_mfma_f32_16x16x32_bf16(a, bw[16 + kk], acc, 0, 0, 0);
    }
    int ko = nt * 16 + col;
    if (ko < 24) {
      float bv = bout[ko];
#pragma unroll
      for (int r = 0; r < 4; ++r) {
        int b = b0 + quad * 4 + r;
        float mk = (y0[(t + 1) * 64 + b] > 0) ? 1.f : 0.f;
        lg[((size_t)t * 64 + b) * 32 + ko] = mk * (acc[r] + bv);
      }
    }
  }
}

// ---------------- CRF forward + gold, one wave per batch ----------------
__global__ __launch_bounds__(64) void crf_kernel(
    const float* __restrict__ lg, const int* __restrict__ y0,
    const float* __restrict__ trans, float* __restrict__ res) {
  int b = blockIdx.x, l = threadIdx.x;
  __shared__ float tl[600];
  __shared__ float sc[24];
  for (int i = l; i < 576; i += 64) tl[(i / 24) * 25 + (i % 24)] = trans[i];
  if (l < 24) sc[l] = (l == 1) ? 0.f : NEGV;
  __syncthreads();
  float gold = 0.f;
  int lens = 0;
  for (int t = l; t < 256; t += 64) {
    int y1 = y0[(t + 1) * 64 + b];
    int yp = y0[t * 64 + b];
    if (y1 > 0) {
      gold += lg[((size_t)t * 64 + b) * 32 + y1] + tl[y1 * 25 + yp];
      lens += 1;
    }
  }
#pragma unroll
  for (int off = 32; off > 0; off >>= 1) {
    gold += __shfl_down(gold, off);
    lens += __shfl_down(lens, off);
  }
  gold = __shfl(gold, 0);
  lens = __shfl(lens, 0);
  int last = y0[lens * 64 + b];
  gold += tl[2 * 25 + last];
  int lc = (l < 24) ? l : 23;
  float trow[24];
#pragma unroll
  for (int j = 0; j < 24; ++j) trow[j] = tl[lc * 25 + j];
  for (int t = 0; t < 256; ++t) {
    int y1 = y0[(t + 1) * 64 + b];
    if (y1 > 0) {
      float ns = 0.f;
      if (l < 24) {
        float ht = lg[((size_t)t * 64 + b) * 32 + l];
        float mx = -3.0e38f;
        float sj[24];
#pragma unroll
        for (int j = 0; j < 24; ++j) {
          sj[j] = sc[j] + trow[j];
          mx = fmaxf(mx, sj[j]);
        }
        float sm = 0.f;
#pragma unroll
        for (int j = 0; j < 24; ++j) sm += __expf(sj[j] - mx);
        ns = ht + mx + __logf(sm);
      }
      __syncthreads();
      if (l < 24) sc[l] = ns;
      __syncthreads();
    }
  }
  float v = (l < 24) ? sc[l] + tl[2 * 25 + l] : -3.0e38f;
  float mx = v;
#pragma unroll
  for (int off = 32; off > 0; off >>= 1) mx = fmaxf(mx, __shfl_xor(mx, off));
  float se = (l < 24) ? __expf(v - mx) : 0.f;
#pragma unroll
  for (int off = 32; off > 0; off >>= 1) se += __shfl_xor(se, off);
  float Z = mx + __logf(se);
  if (l == 0) res[b] = Z - gold;
}

__global__ __launch_bounds__(64) void reduce_kernel(const float* __restrict__ res,
                                                    float* __restrict__ out) {
  int l = threadIdx.x;
  float v = res[l];
#pragma unroll
  for (int off = 32; off > 0; off >>= 1) v += __shfl_down(v, off);
  if (l == 0) out[0] = v * (1.0f / 64.0f);
}

extern "C" void kernel_launch(void* const* d_in, const int* in_sizes, int n_in,
                              void* d_out, int out_size, void* d_ws, size_t ws_size,
                              hipStream_t stream) {
  (void)in_sizes; (void)n_in; (void)out_size; (void)ws_size;
  const int* xw = (const int*)d_in[0];
  const int* y0 = (const int*)d_in[1];
  const float* emb = (const float*)d_in[2];
  const float* wihf = (const float*)d_in[3];
  const float* whhf = (const float*)d_in[4];
  const float* bfv = (const float*)d_in[5];
  const float* wihb = (const float*)d_in[6];
  const float* whhb = (const float*)d_in[7];
  const float* bbv = (const float*)d_in[8];
  const float* wo = (const float*)d_in[9];
  const float* bo = (const float*)d_in[10];
  const float* tr = (const float*)d_in[11];
  char* ws = (char*)d_ws;
  unsigned short* xg = (unsigned short*)(ws + 0);              // 134217728 B
  unsigned short* xbf = (unsigned short*)(ws + 134217728);     // 16777216 B
  unsigned short* wih_c = (unsigned short*)(ws + 150994944);   // 4194304 B
  unsigned short* whh_c = (unsigned short*)(ws + 155189248);   // 4194304 B
  unsigned short* wout_c = (unsigned short*)(ws + 159383552);  // 49152 B
  float* bias_c = (float*)(ws + 159432704);                    // 16384 B
  unsigned short* hfp = (unsigned short*)(ws + 159449088);     // 16777216 B
  unsigned short* hbp = (unsigned short*)(ws + 176226304);     // 16777216 B
  float* lg = (float*)(ws + 193003520);                        // 2097152 B
  float* res = (float*)(ws + 195104768);                       // 256 B

  // pre-poison h planes to the 0xFFFF sentinel (data-is-flag protocol);
  // re-done every launch so graph replays are self-consistent.
  hipMemsetAsync(hfp, 0xFF, 16777216, stream);
  hipMemsetAsync(hbp, 0xFF, 16777216, stream);
  prep_kernel<<<49264, 256, 0, stream>>>(wihf, wihb, whhf, whhb, wo, bfv, bbv,
                                         xw, emb, wih_c, whh_c, wout_c, bias_c, xbf);
  gemm_xg_kernel<<<dim3(128, 32), 256, 0, stream>>>(xbf, wih_c, bias_c, xg);
  scan_kernel<<<512, 64, 0, stream>>>(whh_c, xg, hfp, hbp);
  logits_kernel<<<256, 256, 0, stream>>>(hfp, hbp, wout_c, bo, y0, lg);
  crf_kernel<<<64, 64, 0, stream>>>(lg, y0, tr, res);
  reduce_kernel<<<1, 64, 0, stream>>>(res, (float*)d_out);
}

// Round 14
// 1173.720 us; speedup vs baseline: 1.5071x; 1.0041x over previous
//
#include <hip/hip_runtime.h>

typedef __attribute__((ext_vector_type(8))) short short8;
typedef __attribute__((ext_vector_type(4))) float f32x4;

#define NEGV -10000.0f

__device__ __forceinline__ float bfu2f(unsigned short u) {
  unsigned int x = ((unsigned int)u) << 16;
  return __builtin_bit_cast(float, x);
}
__device__ __forceinline__ unsigned short f2bfu(float f) {
  unsigned int x = __builtin_bit_cast(unsigned int, f);
  x += 0x7fffu + ((x >> 16) & 1u);
  return (unsigned short)(x >> 16);
}
__device__ __forceinline__ float fsig(float x) {
  return 1.0f / (1.0f + __expf(-x));
}
__device__ __forceinline__ float ftanh(float x) {
  x = fminf(15.0f, fmaxf(-15.0f, x));
  float e = __expf(-2.0f * x);
  return (1.0f - e) / (1.0f + e);
}

// ---------------- prep: weights->bf16, combined bias, embedding gather ----------------
__global__ __launch_bounds__(256) void prep_kernel(
    const float* __restrict__ wihf, const float* __restrict__ wihb,
    const float* __restrict__ whhf, const float* __restrict__ whhb,
    const float* __restrict__ wo, const float* __restrict__ bfv,
    const float* __restrict__ bbv, const int* __restrict__ xw,
    const float* __restrict__ emb,
    unsigned short* __restrict__ wih_c, unsigned short* __restrict__ whh_c,
    unsigned short* __restrict__ wout_c, float* __restrict__ bias_c,
    unsigned short* __restrict__ xbf) {
  size_t i = (size_t)blockIdx.x * 256 + threadIdx.x;
  const size_t n_half = 2048u * 512u;        // 1048576
  const size_t n_wih = 2u * n_half;          // 2097152
  const size_t n_wo = 24u * 1024u;           // 24576
  const size_t TOT = 2u * n_wih + n_wo + 4096u;  // 4222976
  if (i < n_wih) {
    float v = (i < n_half) ? wihf[i] : wihb[i - n_half];
    wih_c[i] = f2bfu(v);
  } else if (i < 2u * n_wih) {
    size_t j = i - n_wih;
    float v = (j < n_half) ? whhf[j] : whhb[j - n_half];
    whh_c[j] = f2bfu(v);
  } else if (i < 2u * n_wih + n_wo) {
    size_t j = i - 2u * n_wih;
    wout_c[j] = f2bfu(wo[j]);
  } else if (i < TOT) {
    size_t j = i - 2u * n_wih - n_wo;
    bias_c[j] = (j < 2048u) ? bfv[j] : bbv[j - 2048u];
  } else if (i < TOT + 8388608u) {
    size_t j = i - TOT;
    int tb = (int)(j >> 9), e = (int)(j & 511u);
    xbf[j] = f2bfu(emb[(size_t)xw[tb] * 512 + e]);
  }
}

// ---------------- GEMM (m97 structure): xg = xbf @ wih_c^T + bias ----------------
// 128x128 tile, BK=64. Both operands staged via global_load_lds width-16:
// linear LDS dest + PRE-SWIZZLED global source (rule 21: the source permutation
// equals the read permutation). Read path identical to the proven R11 kernel:
// phys[r*128 + (cb ^ ((r&7)<<4))] == logical(r, cb).
__global__ __launch_bounds__(256) void gemm_xg_kernel(
    const unsigned short* __restrict__ A,   // xbf [16384][512] bf16
    const unsigned short* __restrict__ Bm,  // wih_c [4096][512] bf16
    const float* __restrict__ bias,         // [4096]
    unsigned short* __restrict__ C) {       // [16384][4096] bf16
  __shared__ alignas(16) char As[16384];
  __shared__ alignas(16) char Bs[16384];
  int m0 = blockIdx.x * 128, n0 = blockIdx.y * 128;
  int tid = threadIdx.x;
  int wv = tid >> 6, l = tid & 63;
  int wm = wv >> 1, wn = wv & 1;
  int col = l & 15, quad = l >> 4;
  int src_off[4], lbase[4];
#pragma unroll
  for (int q = 0; q < 4; ++q) {
    int o = q * 4096 + tid * 16;
    int row = o >> 7, p = o & 127;
    src_off[q] = row * 1024 + (p ^ ((row & 7) << 4));
    lbase[q] = q * 4096 + wv * 1024;
  }
  const char* abase = (const char*)A + (size_t)m0 * 1024;
  const char* bbase = (const char*)Bm + (size_t)n0 * 1024;
  f32x4 zero4 = {0.f, 0.f, 0.f, 0.f};
  f32x4 acc[4][4];
#pragma unroll
  for (int i = 0; i < 4; ++i)
#pragma unroll
    for (int j = 0; j < 4; ++j) acc[i][j] = zero4;
  for (int kt = 0; kt < 8; ++kt) {
#pragma unroll
    for (int q = 0; q < 4; ++q) {
      __builtin_amdgcn_global_load_lds(
          (const __attribute__((address_space(1))) void*)(abase + src_off[q] + kt * 128),
          (__attribute__((address_space(3))) void*)(As + lbase[q]), 16, 0, 0);
      __builtin_amdgcn_global_load_lds(
          (const __attribute__((address_space(1))) void*)(bbase + src_off[q] + kt * 128),
          (__attribute__((address_space(3))) void*)(Bs + lbase[q]), 16, 0, 0);
    }
    __syncthreads();
#pragma unroll
    for (int kk = 0; kk < 2; ++kk) {
      short8 af[4], bf8[4];
#pragma unroll
      for (int mi = 0; mi < 4; ++mi) {
        int r = wm * 64 + mi * 16 + col;
        int cb = kk * 64 + quad * 16;
        af[mi] = *(const short8*)(As + r * 128 + (cb ^ ((r & 7) << 4)));
      }
#pragma unroll
      for (int ni = 0; ni < 4; ++ni) {
        int r = wn * 64 + ni * 16 + col;
        int cb = kk * 64 + quad * 16;
        bf8[ni] = *(const short8*)(Bs + r * 128 + (cb ^ ((r & 7) << 4)));
      }
#pragma unroll
      for (int mi = 0; mi < 4; ++mi)
#pragma unroll
        for (int ni = 0; ni < 4; ++ni)
          acc[mi][ni] = __builtin_amdgcn_mfma_f32_16x16x32_bf16(af[mi], bf8[ni], acc[mi][ni], 0, 0, 0);
    }
    __syncthreads();
  }
#pragma unroll
  for (int ni = 0; ni < 4; ++ni) {
    int cg = n0 + wn * 64 + ni * 16 + col;
    float bv = bias[cg];
#pragma unroll
    for (int mi = 0; mi < 4; ++mi) {
#pragma unroll
      for (int r = 0; r < 4; ++r) {
        int rg = m0 + wm * 64 + mi * 16 + quad * 4 + r;
        C[(size_t)rg * 4096 + cg] = f2bfu(acc[mi][ni][r] + bv);
      }
    }
  }
}

// ---------------- persistent LSTM scan: wave-decoupled, poll-on-data (R5-EXACT, proven) ----------------
// 512 wgs x 64 threads. Wave wid: dir=wid&1, g=(wid>>1)&63, wv=(wid>>7)&3.
// h planes pre-poisoned to 0xFFFF (bf16 NaN, unreachable: |h|<1). The data IS
// the flag: producers store 16B chunks (atomic at IF$) with sc0 sc1 and no
// drain; readers re-issue their 16 h-loads until no chunk starts with the
// sentinel. Poll safety: issue -> vmcnt(0) -> check; asm registers never
// consumed while loads in flight (R7 lesson).
__global__ __launch_bounds__(64, 1) void scan_kernel(
    const unsigned short* __restrict__ whh,  // [2][2048][512] bf16
    const unsigned short* __restrict__ xg,   // [16384][4096] bf16
    unsigned short* __restrict__ hfp,
    unsigned short* __restrict__ hbp) {
  __shared__ alignas(16) unsigned short tbuf[128];  // 256B transpose scratch
  int wid = blockIdx.x;
  int l = threadIdx.x;
  int dir = wid & 1;
  int g = (wid >> 1) & 63;
  int wv = (wid >> 7) & 3;
  int u0 = g * 8;
  int col = l & 15, quad = l >> 4;
  int b_row = wv * 16 + quad * 4;
  // asm-resident w_hh fragments: 2 gate-pairs x 16 K-chunks = 128 VGPRs
  short8 bfr[2][16];
#pragma unroll
  for (int n = 0; n < 2; ++n) {
    int blk = n * 2 + (col >> 3);  // 0..3 = i,f,g,o
    int gr = blk * 512 + u0 + (col & 7);
    const char* base = (const char*)(whh + ((size_t)dir * 2048 + gr) * 512 + quad * 8);
#pragma unroll
    for (int kk = 0; kk < 16; ++kk)
      asm volatile("global_load_dwordx4 %0, %1, off" : "=v"(bfr[n][kk]) : "v"(base + kk * 64));
  }
  asm volatile("s_waitcnt vmcnt(0)" ::: "memory");
  unsigned short* hseq = dir ? hbp : hfp;
  float cst[4] = {0.f, 0.f, 0.f, 0.f};
  f32x4 zero4 = {0.f, 0.f, 0.f, 0.f};
  for (int s = 0; s < 256; ++s) {
    int t = dir ? (255 - s) : s;
    // xg loads: plain cached, issued before the poll -> latency hidden
    float xgv[2][4];
#pragma unroll
    for (int n = 0; n < 2; ++n) {
      int gc = dir * 2048 + (n * 2 + (col >> 3)) * 512 + u0 + (col & 7);
#pragma unroll
      for (int r = 0; r < 4; ++r)
        xgv[n][r] = bfu2f(xg[((size_t)t * 64 + b_row + r) * 4096 + gc]);
    }
    f32x4 a0 = zero4, a1 = zero4;
    if (s > 0) {
      int tprev = dir ? (t + 1) : (t - 1);
      const char* pbase = (const char*)hseq + (size_t)tprev * 65536 + quad * 1024 +
                          (wv * 16 + col) * 16;
      short8 af[16];
      unsigned long long bal;
      do {
#pragma unroll
        for (int kk = 0; kk < 16; ++kk)
          asm volatile("global_load_dwordx4 %0, %1, off sc0 sc1" : "=v"(af[kk]) : "v"(pbase + kk * 4096));
        asm volatile("s_waitcnt vmcnt(0)" ::: "memory");
        unsigned int anystale = 0u;
#pragma unroll
        for (int kk = 0; kk < 16; ++kk)
          anystale |= (((unsigned short)af[kk][0]) == 0xFFFFu) ? 1u : 0u;
        bal = __ballot(anystale != 0u);
      } while (bal != 0ull);
      __builtin_amdgcn_sched_barrier(0);
#pragma unroll
      for (int kk = 0; kk < 16; ++kk) {
        a0 = __builtin_amdgcn_mfma_f32_16x16x32_bf16(af[kk], bfr[0][kk], a0, 0, 0, 0);
        a1 = __builtin_amdgcn_mfma_f32_16x16x32_bf16(af[kk], bfr[1][kk], a1, 0, 0, 0);
      }
    }
    // gates; low/high lane pairs compute identical h, low lanes write LDS
    {
      bool low = (col < 8);
#pragma unroll
      for (int r = 0; r < 4; ++r) {
        float g0 = a0[r] + xgv[0][r];
        float g1 = a1[r] + xgv[1][r];
        float p0 = __shfl_xor(g0, 8);
        float p1 = __shfl_xor(g1, 8);
        float iv = low ? g0 : p0;
        float fv = low ? p0 : g0;
        float gv = low ? g1 : p1;
        float ov = low ? p1 : g1;
        float cn = fsig(fv) * cst[r] + fsig(iv) * ftanh(gv);
        cst[r] = cn;
        float hv = fsig(ov) * ftanh(cn);
        if (low) tbuf[(quad * 4 + r) * 8 + (col & 7)] = f2bfu(hv);
      }
    }
    // wave-internal transpose readback (same wave: lgkmcnt suffices, no barrier)
    asm volatile("s_waitcnt lgkmcnt(0)" ::: "memory");
    if (l < 16) {
      short8 hrow = *(const short8*)(tbuf + l * 8);
      char* dst = (char*)hseq + (size_t)t * 65536 + g * 1024 + (wv * 16 + l) * 16;
      asm volatile("global_store_dwordx4 %0, %1, off sc0 sc1" :: "v"(dst), "v"(hrow) : "memory");
    }
    // no drain, no flag: the store IS the publish; it retires in background
  }
}

// ---------------- logits via MFMA: lg[t][b][k] = mask*( (hf|hb)@wout^T + bout ) ----------------
__global__ __launch_bounds__(256) void logits_kernel(
    const unsigned short* __restrict__ hfp, const unsigned short* __restrict__ hbp,
    const unsigned short* __restrict__ wout, const float* __restrict__ bout,
    const int* __restrict__ y0, float* __restrict__ lg) {
  int t = blockIdx.x;
  int w = threadIdx.x >> 6, l = threadIdx.x & 63;
  int nt = w & 1, mh = w >> 1;
  int col = l & 15, quad = l >> 4;
  int wr = nt * 16 + col;
  if (wr > 23) wr = 23;
  short8 bw[32];
#pragma unroll
  for (int kk = 0; kk < 32; ++kk)
    bw[kk] = *(const short8*)(wout + (size_t)wr * 1024 + kk * 32 + quad * 8);
  f32x4 zero4 = {0.f, 0.f, 0.f, 0.f};
  const char* pf = (const char*)hfp + (size_t)t * 65536;
  const char* pb = (const char*)hbp + (size_t)t * 65536;
#pragma unroll
  for (int mt = 0; mt < 2; ++mt) {
    int b0 = mh * 32 + mt * 16;
    f32x4 acc = zero4;
#pragma unroll
    for (int kk = 0; kk < 16; ++kk) {
      short8 a = *(const short8*)(pf + (kk * 4 + quad) * 1024 + (b0 + col) * 16);
      acc = __builtin_amdgcn_mfma_f32_16x16x32_bf16(a, bw[kk], acc, 0, 0, 0);
    }
#pragma unroll
    for (int kk = 0; kk < 16; ++kk) {
      short8 a = *(const short8*)(pb + (kk * 4 + quad) * 1024 + (b0 + col) * 16);
      acc = __builtin_amdgcn_mfma_f32_16x16x32_bf16(a, bw[16 + kk], acc, 0, 0, 0);
    }
    int ko = nt * 16 + col;
    if (ko < 24) {
      float bv = bout[ko];
#pragma unroll
      for (int r = 0; r < 4; ++r) {
        int b = b0 + quad * 4 + r;
        float mk = (y0[(t + 1) * 64 + b] > 0) ? 1.f : 0.f;
        lg[((size_t)t * 64 + b) * 32 + ko] = mk * (acc[r] + bv);
      }
    }
  }
}

// ---------------- CRF forward + gold, one wave per batch ----------------
__global__ __launch_bounds__(64) void crf_kernel(
    const float* __restrict__ lg, const int* __restrict__ y0,
    const float* __restrict__ trans, float* __restrict__ res) {
  int b = blockIdx.x, l = threadIdx.x;
  __shared__ float tl[600];
  __shared__ float sc[24];
  for (int i = l; i < 576; i += 64) tl[(i / 24) * 25 + (i % 24)] = trans[i];
  if (l < 24) sc[l] = (l == 1) ? 0.f : NEGV;
  __syncthreads();
  float gold = 0.f;
  int lens = 0;
  for (int t = l; t < 256; t += 64) {
    int y1 = y0[(t + 1) * 64 + b];
    int yp = y0[t * 64 + b];
    if (y1 > 0) {
      gold += lg[((size_t)t * 64 + b) * 32 + y1] + tl[y1 * 25 + yp];
      lens += 1;
    }
  }
#pragma unroll
  for (int off = 32; off > 0; off >>= 1) {
    gold += __shfl_down(gold, off);
    lens += __shfl_down(lens, off);
  }
  gold = __shfl(gold, 0);
  lens = __shfl(lens, 0);
  int last = y0[lens * 64 + b];
  gold += tl[2 * 25 + last];
  int lc = (l < 24) ? l : 23;
  float trow[24];
#pragma unroll
  for (int j = 0; j < 24; ++j) trow[j] = tl[lc * 25 + j];
  for (int t = 0; t < 256; ++t) {
    int y1 = y0[(t + 1) * 64 + b];
    if (y1 > 0) {
      float ns = 0.f;
      if (l < 24) {
        float ht = lg[((size_t)t * 64 + b) * 32 + l];
        float mx = -3.0e38f;
        float sj[24];
#pragma unroll
        for (int j = 0; j < 24; ++j) {
          sj[j] = sc[j] + trow[j];
          mx = fmaxf(mx, sj[j]);
        }
        float sm = 0.f;
#pragma unroll
        for (int j = 0; j < 24; ++j) sm += __expf(sj[j] - mx);
        ns = ht + mx + __logf(sm);
      }
      __syncthreads();
      if (l < 24) sc[l] = ns;
      __syncthreads();
    }
  }
  float v = (l < 24) ? sc[l] + tl[2 * 25 + l] : -3.0e38f;
  float mx = v;
#pragma unroll
  for (int off = 32; off > 0; off >>= 1) mx = fmaxf(mx, __shfl_xor(mx, off));
  float se = (l < 24) ? __expf(v - mx) : 0.f;
#pragma unroll
  for (int off = 32; off > 0; off >>= 1) se += __shfl_xor(se, off);
  float Z = mx + __logf(se);
  if (l == 0) res[b] = Z - gold;
}

__global__ __launch_bounds__(64) void reduce_kernel(const float* __restrict__ res,
                                                    float* __restrict__ out) {
  int l = threadIdx.x;
  float v = res[l];
#pragma unroll
  for (int off = 32; off > 0; off >>= 1) v += __shfl_down(v, off);
  if (l == 0) out[0] = v * (1.0f / 64.0f);
}

extern "C" void kernel_launch(void* const* d_in, const int* in_sizes, int n_in,
                              void* d_out, int out_size, void* d_ws, size_t ws_size,
                              hipStream_t stream) {
  (void)in_sizes; (void)n_in; (void)out_size; (void)ws_size;
  const int* xw = (const int*)d_in[0];
  const int* y0 = (const int*)d_in[1];
  const float* emb = (const float*)d_in[2];
  const float* wihf = (const float*)d_in[3];
  const float* whhf = (const float*)d_in[4];
  const float* bfv = (const float*)d_in[5];
  const float* wihb = (const float*)d_in[6];
  const float* whhb = (const float*)d_in[7];
  const float* bbv = (const float*)d_in[8];
  const float* wo = (const float*)d_in[9];
  const float* bo = (const float*)d_in[10];
  const float* tr = (const float*)d_in[11];
  char* ws = (char*)d_ws;
  unsigned short* xg = (unsigned short*)(ws + 0);              // 134217728 B
  unsigned short* xbf = (unsigned short*)(ws + 134217728);     // 16777216 B
  unsigned short* wih_c = (unsigned short*)(ws + 150994944);   // 4194304 B
  unsigned short* whh_c = (unsigned short*)(ws + 155189248);   // 4194304 B
  unsigned short* wout_c = (unsigned short*)(ws + 159383552);  // 49152 B
  float* bias_c = (float*)(ws + 159432704);                    // 16384 B
  unsigned short* hfp = (unsigned short*)(ws + 159449088);     // 16777216 B
  unsigned short* hbp = (unsigned short*)(ws + 176226304);     // 16777216 B
  float* lg = (float*)(ws + 193003520);                        // 2097152 B
  float* res = (float*)(ws + 195104768);                       // 256 B

  // pre-poison h planes to the 0xFFFF sentinel (data-is-flag protocol);
  // re-done every launch so graph replays are self-consistent.
  hipMemsetAsync(hfp, 0xFF, 16777216, stream);
  hipMemsetAsync(hbp, 0xFF, 16777216, stream);
  prep_kernel<<<49264, 256, 0, stream>>>(wihf, wihb, whhf, whhb, wo, bfv, bbv,
                                         xw, emb, wih_c, whh_c, wout_c, bias_c, xbf);
  gemm_xg_kernel<<<dim3(128, 32), 256, 0, stream>>>(xbf, wih_c, bias_c, xg);
  scan_kernel<<<512, 64, 0, stream>>>(whh_c, xg, hfp, hbp);
  logits_kernel<<<256, 256, 0, stream>>>(hfp, hbp, wout_c, bo, y0, lg);
  crf_kernel<<<64, 64, 0, stream>>>(lg, y0, tr, res);
  reduce_kernel<<<1, 64, 0, stream>>>(res, (float*)d_out);
}